// Round 6
// baseline (726.630 us; speedup 1.0000x reference)
//
#include <hip/hip_runtime.h>
#include <hip/hip_bf16.h>

typedef __bf16 bf16;
typedef bf16 bf16x8 __attribute__((ext_vector_type(8)));
typedef float f32x4 __attribute__((ext_vector_type(4)));
typedef unsigned short u16;

#define B_ 4
#define S_ 2048
#define D_ 1024
#define H_ 16
#define HD_ 64

#define NEG_SENT -30000.0f

// workspace layout (bf16 element offsets)
#define XN_OFF   ((size_t)0)          // 8388608 elems; reused as Ab after QKV
#define WT_OFF   ((size_t)8388608)    // 4 x 1048576
#define BN_OFF   ((size_t)12582912)   // 4 x 1024
#define FLAG_BYTE ((size_t)25174016)  // int flag
#define Q_OFF    ((size_t)12587520)
#define K_OFF    ((size_t)20976128)
#define VT_OFF   ((size_t)29364736)

union Pack4 { bf16 b[4]; uint2 q; };

__device__ __forceinline__ void load16(const bf16* g, bf16* l) {
    __builtin_amdgcn_global_load_lds(
        (const __attribute__((address_space(1))) void*)g,
        (__attribute__((address_space(3))) void*)l, 16, 0, 0);
}

// ---------------- dtype detection ----------------
__global__ __launch_bounds__(256) void detect_k(const u16* __restrict__ x,
                                                int* __restrict__ flag)
{
    __shared__ int cnt;
    if (threadIdx.x == 0) cnt = 0;
    __syncthreads();
    int c = 0;
    for (int i = threadIdx.x; i < 4096; i += 256) {
        u16 w = x[i * 2];            // even-indexed words
        int e = (w >> 7) & 0xFF;
        if (e >= 100 && e <= 135) c++;
    }
    atomicAdd(&cnt, c);
    __syncthreads();
    if (threadIdx.x == 0) *flag = (cnt > 2048) ? 1 : 0;   // 1 = bf16
}

// ---------------- input normalization: x -> bf16 XN ----------------
__global__ __launch_bounds__(256) void norm_x_k(const void* __restrict__ src,
                                                bf16* __restrict__ dst,
                                                const int* __restrict__ flag)
{
    const int qi = blockIdx.x * 256 + threadIdx.x;   // quad index, 4 elems each
    if (*flag) {
        ((uint2*)dst)[qi] = ((const uint2*)src)[qi];
    } else {
        float4 v = ((const float4*)src)[qi];
        Pack4 p;
        p.b[0] = (bf16)v.x; p.b[1] = (bf16)v.y;
        p.b[2] = (bf16)v.z; p.b[3] = (bf16)v.w;
        ((uint2*)dst)[qi] = p.q;
    }
}

// ---------------- bias normalization ----------------
__global__ __launch_bounds__(256) void norm_b_k(
    const void* __restrict__ b0, const void* __restrict__ b1,
    const void* __restrict__ b2, const void* __restrict__ b3,
    bf16* __restrict__ BN, const int* __restrict__ flag)
{
    const int mat = blockIdx.x;
    const void* src = (mat == 0) ? b0 : (mat == 1) ? b1 : (mat == 2) ? b2 : b3;
    bf16* dst = BN + mat * 1024;
    const int i = threadIdx.x * 4;
    if (*flag) {
        ((uint2*)(dst + i))[0] = *(const uint2*)((const bf16*)src + i);
    } else {
        const float* s = (const float*)src;
        Pack4 p;
        p.b[0] = (bf16)s[i + 0]; p.b[1] = (bf16)s[i + 1];
        p.b[2] = (bf16)s[i + 2]; p.b[3] = (bf16)s[i + 3];
        ((uint2*)(dst + i))[0] = p.q;
    }
}

// ---------- weight normalize + transpose: W[K][N] -> WT[N][K] (bf16) ----------
__global__ __launch_bounds__(256) void transpose_w(
    const void* __restrict__ W0, const void* __restrict__ W1,
    const void* __restrict__ W2, const void* __restrict__ W3,
    bf16* __restrict__ WT, const int* __restrict__ flag)
{
    __shared__ __align__(16) bf16 tile[64][65];
    const int mat = blockIdx.z;
    const void* W = (mat == 0) ? W0 : (mat == 1) ? W1 : (mat == 2) ? W2 : W3;
    bf16* O = WT + ((size_t)mat << 20);
    const int r0 = blockIdx.y * 64, c0 = blockIdx.x * 64;
    const int t = threadIdx.x;
    const int isb = *flag;
    #pragma unroll
    for (int i = 0; i < 16; ++i) {
        int idx = t + i * 256;
        int r = idx >> 6, c = idx & 63;
        size_t off = (size_t)(r0 + r) * D_ + c0 + c;
        tile[r][c] = isb ? ((const bf16*)W)[off] : (bf16)((const float*)W)[off];
    }
    __syncthreads();
    #pragma unroll
    for (int i = 0; i < 16; ++i) {
        int idx = t + i * 256;
        int rr = idx & 63, cc = idx >> 6;
        O[(size_t)(c0 + cc) * D_ + r0 + rr] = tile[rr][cc];
    }
}

// ---------------- shared 128x128 GEMM mainloop (m97 structure) ----------------
__device__ __forceinline__ void gemm_core(const bf16* __restrict__ A,
                                          const bf16* __restrict__ Bt,
                                          bf16* lA, bf16* lB,
                                          f32x4 acc[4][4], int m0, int n0)
{
    const int t = threadIdx.x;
    const int lane = t & 63;
    const int wave = t >> 6;
    const int wm = (wave >> 1) << 6;
    const int wn = (wave & 1) << 6;
    const int quad = lane >> 4;
    const int col = lane & 15;
    for (int k0 = 0; k0 < D_; k0 += 32) {
        #pragma unroll
        for (int i = 0; i < 2; ++i) {
            int slot = t + i * 256;
            int row = slot >> 2;
            int kc = (slot & 3) << 3;
            load16(A + (size_t)(m0 + row) * D_ + k0 + kc, lA + slot * 8);
            load16(Bt + (size_t)(n0 + row) * D_ + k0 + kc, lB + slot * 8);
        }
        __syncthreads();
        bf16x8 af[4], bfr[4];
        #pragma unroll
        for (int mi = 0; mi < 4; ++mi)
            af[mi] = *(const bf16x8*)(lA + (wm + mi * 16 + col) * 32 + quad * 8);
        #pragma unroll
        for (int ni = 0; ni < 4; ++ni)
            bfr[ni] = *(const bf16x8*)(lB + (wn + ni * 16 + col) * 32 + quad * 8);
        #pragma unroll
        for (int mi = 0; mi < 4; ++mi)
            #pragma unroll
            for (int ni = 0; ni < 4; ++ni)
                acc[mi][ni] = __builtin_amdgcn_mfma_f32_16x16x32_bf16(
                    af[mi], bfr[ni], acc[mi][ni], 0, 0, 0);
        __syncthreads();
    }
}

// ---------------- QKV projection ----------------
// mode 0: Q scaled by (1/8)*log2(e) -> [b][h][s][hd]; mode 1: K; mode 2: V^T
__global__ __launch_bounds__(256) void gemm_qkv_k(
    const bf16* __restrict__ X, const bf16* __restrict__ WT,
    const bf16* __restrict__ BN,
    bf16* __restrict__ Qo, bf16* __restrict__ Ko, bf16* __restrict__ Vo)
{
    __shared__ __align__(16) bf16 lA[128 * 32];
    __shared__ __align__(16) bf16 lB[128 * 32];
    const int mode = blockIdx.z;
    const bf16* Wsel = WT + ((size_t)mode << 20);
    const bf16* bias = BN + mode * 1024;
    f32x4 acc[4][4];
    const f32x4 z = {0.f, 0.f, 0.f, 0.f};
    #pragma unroll
    for (int i = 0; i < 4; ++i)
        #pragma unroll
        for (int j = 0; j < 4; ++j) acc[i][j] = z;
    const int m0 = blockIdx.x * 128, n0 = blockIdx.y * 128;
    gemm_core(X, Wsel, lA, lB, acc, m0, n0);
    const int t = threadIdx.x, lane = t & 63, wave = t >> 6;
    const int wm = (wave >> 1) << 6, wn = (wave & 1) << 6;
    const int quad = lane >> 4, col = lane & 15;
    // 0.125 * log2(e): softmax later uses raw exp2
    const float scale = (mode == 0) ? 0.18033688011112042f : 1.0f;
    #pragma unroll
    for (int mi = 0; mi < 4; ++mi) {
        int gm = m0 + wm + mi * 16 + quad * 4;
        int b = gm >> 11, srow = gm & 2047;
        #pragma unroll
        for (int ni = 0; ni < 4; ++ni) {
            int gn = n0 + wn + ni * 16 + col;
            float bb = (float)bias[gn];
            int h = gn >> 6, hd = gn & 63;
            #pragma unroll
            for (int r = 0; r < 4; ++r) {
                float v = (acc[mi][ni][r] + bb) * scale;
                if (mode == 2)
                    Vo[(((size_t)b * H_ + h) * HD_ + hd) * S_ + srow + r] = (bf16)v;
                else if (mode == 1)
                    Ko[(((size_t)b * H_ + h) * S_ + srow + r) * HD_ + hd] = (bf16)v;
                else
                    Qo[(((size_t)b * H_ + h) * S_ + srow + r) * HD_ + hd] = (bf16)v;
            }
        }
    }
}

// ---------------- flash attention (causal), S^T/O^T form, K-tile=128 --------
// grid: (S/64, B*H). block: 256 = 4 waves; wave w owns 16 q rows.
// S^T = K·Q^T; O^T = V^T·P^T. XOR-swizzled LDS. Fully-masked 16-k subtiles
// skipped via wave-uniform inc[] guards. One softmax chain / staging drain /
// barrier pair per 128 k (halves latency overhead per unit vs K-tile 64).
__global__ __launch_bounds__(256) void attn_k(
    const bf16* __restrict__ Q, const bf16* __restrict__ K,
    const bf16* __restrict__ VT, bf16* __restrict__ Aout)
{
    __shared__ __align__(16) bf16 lK[128 * 64];      // [k][d], chunk^=(k&7)
    __shared__ __align__(16) bf16 lV[64 * 128];      // [d][k], chunk^=(d&7)
    __shared__ __align__(16) bf16 lPT[4][16 * 128];  // per-wave [q][k], ^=(q&7)
    const int bh = blockIdx.y;
    const int qc = (int)gridDim.x - 1 - (int)blockIdx.x; // big blocks first
    const int q0 = qc * 64;
    const bf16* Qp = Q + (size_t)bh * S_ * HD_;
    const bf16* Kp = K + (size_t)bh * S_ * HD_;
    const bf16* Vp = VT + (size_t)bh * HD_ * S_;
    const int t = threadIdx.x, lane = t & 63, w = t >> 6;
    const int quad = lane >> 4, col = lane & 15;
    const int wq0 = q0 + w * 16;

    // Q fragments (B-operand): B[n=q][k=d], n=col, k=quad*8+j
    bf16x8 qf[2];
    #pragma unroll
    for (int cc = 0; cc < 2; ++cc)
        qf[cc] = *(const bf16x8*)(Qp + (size_t)(wq0 + col) * HD_
                                  + cc * 32 + quad * 8);
    f32x4 o[4];               // O^T acc per d-tile; q = col
    float mst = NEG_SENT, lst = 0.f;
    const f32x4 z = {0.f, 0.f, 0.f, 0.f};
    #pragma unroll
    for (int dt = 0; dt < 4; ++dt) o[dt] = z;

    const int kend = q0 + 64;
    for (int k0 = 0; k0 < kend; k0 += 128) {
        // stage K[k0:+128][0:64] and V^T[0:64][k0:+128], xor-swizzled 8-chunks
        #pragma unroll
        for (int i = 0; i < 4; ++i) {
            int slot = t + i * 256;          // 0..1023
            int rk = slot >> 3, chk = slot & 7;
            load16(Kp + (size_t)(k0 + rk) * HD_ + ((chk ^ (rk & 7)) << 3),
                   lK + slot * 8);
            int dd = slot >> 4, chv = slot & 15;
            load16(Vp + (size_t)dd * S_ + k0 + ((chv ^ (dd & 7)) << 3),
                   lV + slot * 8);
        }
        __syncthreads();
        if (k0 < wq0 + 16) {
            bool inc[8];
            #pragma unroll
            for (int mt = 0; mt < 8; ++mt)
                inc[mt] = (k0 + 16 * mt <= wq0 + 15);
            // S^T[mt=k] = K·Q^T
            f32x4 st[8];
            #pragma unroll
            for (int mt = 0; mt < 8; ++mt) st[mt] = z;
            #pragma unroll
            for (int cc = 0; cc < 2; ++cc) {
                #pragma unroll
                for (int mt = 0; mt < 8; ++mt)
                    if (inc[mt]) {
                        bf16x8 af = *(const bf16x8*)(lK + (mt * 16 + col) * 64
                                    + (((cc * 4 + quad) ^ (col & 7)) << 3));
                        st[mt] = __builtin_amdgcn_mfma_f32_16x16x32_bf16(
                            af, qf[cc], st[mt], 0, 0, 0);
                    }
            }
            if (k0 + 128 > wq0) { // diagonal region: mask k > q
                #pragma unroll
                for (int mt = 0; mt < 8; ++mt)
                    if (inc[mt]) {
                        #pragma unroll
                        for (int r = 0; r < 4; ++r)
                            if (k0 + mt * 16 + quad * 4 + r > wq0 + col)
                                st[mt][r] = NEG_SENT;
                    }
            }
            // online softmax per q (= col): reg reduce + 2 shuffles
            float tm = fmaxf(fmaxf(st[0][0], st[0][1]),
                             fmaxf(st[0][2], st[0][3]));
            #pragma unroll
            for (int mt = 1; mt < 8; ++mt)
                if (inc[mt]) {
                    #pragma unroll
                    for (int r = 0; r < 4; ++r) tm = fmaxf(tm, st[mt][r]);
                }
            tm = fmaxf(tm, __shfl_xor(tm, 16));
            tm = fmaxf(tm, __shfl_xor(tm, 32));
            float mn = fmaxf(mst, tm);
            float al = exp2f(mst - mn);
            mst = mn;
            float ssum = 0.f;
            #pragma unroll
            for (int mt = 0; mt < 8; ++mt)
                if (inc[mt]) {
                    #pragma unroll
                    for (int r = 0; r < 4; ++r) {
                        float p = exp2f(st[mt][r] - mn);
                        st[mt][r] = p;
                        ssum += p;
                    }
                }
            ssum += __shfl_xor(ssum, 16);
            ssum += __shfl_xor(ssum, 32);
            lst = lst * al + ssum;
            #pragma unroll
            for (int dt = 0; dt < 4; ++dt) o[dt] *= al;
            // P^T -> lPT[w] as [q][k]; zero-fill odd subtile of a live kk pair
            #pragma unroll
            for (int mt = 0; mt < 8; ++mt) {
                int kch = mt * 2 + (quad >> 1);
                uint2* dst = (uint2*)(&lPT[w][col * 128 + ((kch ^ (col & 7)) << 3)
                                             + ((quad & 1) << 2)]);
                if (inc[mt]) {
                    Pack4 pk;
                    #pragma unroll
                    for (int r = 0; r < 4; ++r) pk.b[r] = (bf16)st[mt][r];
                    *dst = pk.q;
                } else if ((mt & 1) && inc[mt - 1]) {
                    uint2 zz; zz.x = 0u; zz.y = 0u;
                    *dst = zz;
                }
            }
            // drain P writes before same-wave cross-lane reads
            asm volatile("s_waitcnt lgkmcnt(0)" ::: "memory");
            // O^T += V^T · P^T
            #pragma unroll
            for (int kk = 0; kk < 4; ++kk) {
                if (!inc[2 * kk]) continue;
                bf16x8 pf = *(const bf16x8*)(&lPT[w][col * 128
                            + (((kk * 4 + quad) ^ (col & 7)) << 3)]);
                #pragma unroll
                for (int dt = 0; dt < 4; ++dt) {
                    bf16x8 vf = *(const bf16x8*)(lV + (dt * 16 + col) * 128
                                + (((kk * 4 + quad) ^ (col & 7)) << 3));
                    o[dt] = __builtin_amdgcn_mfma_f32_16x16x32_bf16(
                        vf, pf, o[dt], 0, 0, 0);
                }
            }
        }
        __syncthreads();
    }
    const int b = bh >> 4, h = bh & 15;
    const float inv = 1.f / fmaxf(lst, 1e-30f);
    const int qg = wq0 + col;
    #pragma unroll
    for (int dt = 0; dt < 4; ++dt) {
        Pack4 pk;
        #pragma unroll
        for (int r = 0; r < 4; ++r) pk.b[r] = (bf16)(o[dt][r] * inv);
        *(uint2*)(Aout + ((size_t)b * S_ + qg) * D_ + h * HD_
                  + dt * 16 + quad * 4) = pk.q;
    }
}

// ---------------- output projection (dtype-aware store) ----------------
__global__ __launch_bounds__(256) void gemm_out_k(
    const bf16* __restrict__ A, const bf16* __restrict__ WoT,
    const bf16* __restrict__ Bo, void* __restrict__ Out,
    const int* __restrict__ flag)
{
    __shared__ __align__(16) bf16 lA[128 * 32];
    __shared__ __align__(16) bf16 lB[128 * 32];
    f32x4 acc[4][4];
    const f32x4 z = {0.f, 0.f, 0.f, 0.f};
    #pragma unroll
    for (int i = 0; i < 4; ++i)
        #pragma unroll
        for (int j = 0; j < 4; ++j) acc[i][j] = z;
    const int m0 = blockIdx.x * 128, n0 = blockIdx.y * 128;
    gemm_core(A, WoT, lA, lB, acc, m0, n0);
    const int t = threadIdx.x, lane = t & 63, wave = t >> 6;
    const int wm = (wave >> 1) << 6, wn = (wave & 1) << 6;
    const int quad = lane >> 4, col = lane & 15;
    const int isb = *flag;
    #pragma unroll
    for (int mi = 0; mi < 4; ++mi) {
        int gm = m0 + wm + mi * 16 + quad * 4;
        #pragma unroll
        for (int ni = 0; ni < 4; ++ni) {
            int gn = n0 + wn + ni * 16 + col;
            float bb = (float)Bo[gn];
            #pragma unroll
            for (int r = 0; r < 4; ++r) {
                float v = acc[mi][ni][r] + bb;
                size_t off = (size_t)(gm + r) * D_ + gn;
                if (isb) ((bf16*)Out)[off] = (bf16)v;
                else     ((float*)Out)[off] = v;
            }
        }
    }
}

extern "C" void kernel_launch(void* const* d_in, const int* in_sizes, int n_in,
                              void* d_out, int out_size, void* d_ws, size_t ws_size,
                              hipStream_t stream)
{
    const void* x  = d_in[0];
    const void* wq = d_in[1];
    const void* bq = d_in[2];
    const void* wk = d_in[3];
    const void* bk = d_in[4];
    const void* wv = d_in[5];
    const void* bv = d_in[6];
    const void* wo = d_in[7];
    const void* bo = d_in[8];

    bf16* ws  = (bf16*)d_ws;
    bf16* XN  = ws + XN_OFF;                 // also reused as Ab
    bf16* WT  = ws + WT_OFF;
    bf16* BN  = ws + BN_OFF;
    int*  flag = (int*)((char*)d_ws + FLAG_BYTE);
    bf16* Qb  = ws + Q_OFF;
    bf16* Kb  = ws + K_OFF;
    bf16* VTb = ws + VT_OFF;
    bf16* Ab  = XN;

    hipLaunchKernelGGL(detect_k, dim3(1), dim3(256), 0, stream,
                       (const u16*)x, flag);
    hipLaunchKernelGGL(norm_x_k, dim3(8192), dim3(256), 0, stream,
                       x, XN, flag);
    hipLaunchKernelGGL(transpose_w, dim3(16, 16, 4), dim3(256), 0, stream,
                       wq, wk, wv, wo, WT, flag);
    hipLaunchKernelGGL(norm_b_k, dim3(4), dim3(256), 0, stream,
                       bq, bk, bv, bo, BN, flag);
    hipLaunchKernelGGL(gemm_qkv_k, dim3(64, 8, 3), dim3(256), 0, stream,
                       XN, WT, BN, Qb, Kb, VTb);
    hipLaunchKernelGGL(attn_k, dim3(32, 64), dim3(256), 0, stream,
                       Qb, Kb, VTb, Ab);
    hipLaunchKernelGGL(gemm_out_k, dim3(64, 8), dim3(256), 0, stream,
                       Ab, WT + ((size_t)3u << 20), BN + 3072, d_out, flag);
}

// Round 7
// 382.004 us; speedup vs baseline: 1.9022x; 1.9022x over previous
//
#include <hip/hip_runtime.h>
#include <hip/hip_bf16.h>

typedef __bf16 bf16;
typedef bf16 bf16x8 __attribute__((ext_vector_type(8)));
typedef float f32x4 __attribute__((ext_vector_type(4)));
typedef unsigned short u16;

#define B_ 4
#define S_ 2048
#define D_ 1024
#define H_ 16
#define HD_ 64

#define NEG_SENT -30000.0f

// workspace layout (bf16 element offsets)
#define XN_OFF   ((size_t)0)          // 8388608 elems; reused as Ab after QKV
#define WT_OFF   ((size_t)8388608)    // 4 x 1048576
#define BN_OFF   ((size_t)12582912)   // 4 x 1024
#define FLAG_BYTE ((size_t)25174016)  // int flag
#define Q_OFF    ((size_t)12587520)
#define K_OFF    ((size_t)20976128)
#define VT_OFF   ((size_t)29364736)

union Pack4 { bf16 b[4]; uint2 q; };

__device__ __forceinline__ void load16(const bf16* g, bf16* l) {
    __builtin_amdgcn_global_load_lds(
        (const __attribute__((address_space(1))) void*)g,
        (__attribute__((address_space(3))) void*)l, 16, 0, 0);
}

// ---------------- dtype detection ----------------
__global__ __launch_bounds__(256) void detect_k(const u16* __restrict__ x,
                                                int* __restrict__ flag)
{
    __shared__ int cnt;
    if (threadIdx.x == 0) cnt = 0;
    __syncthreads();
    int c = 0;
    for (int i = threadIdx.x; i < 4096; i += 256) {
        u16 w = x[i * 2];            // even-indexed words
        int e = (w >> 7) & 0xFF;
        if (e >= 100 && e <= 135) c++;
    }
    atomicAdd(&cnt, c);
    __syncthreads();
    if (threadIdx.x == 0) *flag = (cnt > 2048) ? 1 : 0;   // 1 = bf16
}

// ---------------- input normalization: x -> bf16 XN ----------------
__global__ __launch_bounds__(256) void norm_x_k(const void* __restrict__ src,
                                                bf16* __restrict__ dst,
                                                const int* __restrict__ flag)
{
    const int qi = blockIdx.x * 256 + threadIdx.x;   // quad index, 4 elems each
    if (*flag) {
        ((uint2*)dst)[qi] = ((const uint2*)src)[qi];
    } else {
        float4 v = ((const float4*)src)[qi];
        Pack4 p;
        p.b[0] = (bf16)v.x; p.b[1] = (bf16)v.y;
        p.b[2] = (bf16)v.z; p.b[3] = (bf16)v.w;
        ((uint2*)dst)[qi] = p.q;
    }
}

// ---------------- bias normalization ----------------
__global__ __launch_bounds__(256) void norm_b_k(
    const void* __restrict__ b0, const void* __restrict__ b1,
    const void* __restrict__ b2, const void* __restrict__ b3,
    bf16* __restrict__ BN, const int* __restrict__ flag)
{
    const int mat = blockIdx.x;
    const void* src = (mat == 0) ? b0 : (mat == 1) ? b1 : (mat == 2) ? b2 : b3;
    bf16* dst = BN + mat * 1024;
    const int i = threadIdx.x * 4;
    if (*flag) {
        ((uint2*)(dst + i))[0] = *(const uint2*)((const bf16*)src + i);
    } else {
        const float* s = (const float*)src;
        Pack4 p;
        p.b[0] = (bf16)s[i + 0]; p.b[1] = (bf16)s[i + 1];
        p.b[2] = (bf16)s[i + 2]; p.b[3] = (bf16)s[i + 3];
        ((uint2*)(dst + i))[0] = p.q;
    }
}

// ---------- weight normalize + transpose: W[K][N] -> WT[N][K] (bf16) ----------
__global__ __launch_bounds__(256) void transpose_w(
    const void* __restrict__ W0, const void* __restrict__ W1,
    const void* __restrict__ W2, const void* __restrict__ W3,
    bf16* __restrict__ WT, const int* __restrict__ flag)
{
    __shared__ __align__(16) bf16 tile[64][65];
    const int mat = blockIdx.z;
    const void* W = (mat == 0) ? W0 : (mat == 1) ? W1 : (mat == 2) ? W2 : W3;
    bf16* O = WT + ((size_t)mat << 20);
    const int r0 = blockIdx.y * 64, c0 = blockIdx.x * 64;
    const int t = threadIdx.x;
    const int isb = *flag;
    #pragma unroll
    for (int i = 0; i < 16; ++i) {
        int idx = t + i * 256;
        int r = idx >> 6, c = idx & 63;
        size_t off = (size_t)(r0 + r) * D_ + c0 + c;
        tile[r][c] = isb ? ((const bf16*)W)[off] : (bf16)((const float*)W)[off];
    }
    __syncthreads();
    #pragma unroll
    for (int i = 0; i < 16; ++i) {
        int idx = t + i * 256;
        int rr = idx & 63, cc = idx >> 6;
        O[(size_t)(c0 + cc) * D_ + r0 + rr] = tile[rr][cc];
    }
}

// ---------------- shared 128x128 GEMM mainloop (m97 structure) ----------------
__device__ __forceinline__ void gemm_core(const bf16* __restrict__ A,
                                          const bf16* __restrict__ Bt,
                                          bf16* lA, bf16* lB,
                                          f32x4 acc[4][4], int m0, int n0)
{
    const int t = threadIdx.x;
    const int lane = t & 63;
    const int wave = t >> 6;
    const int wm = (wave >> 1) << 6;
    const int wn = (wave & 1) << 6;
    const int quad = lane >> 4;
    const int col = lane & 15;
    for (int k0 = 0; k0 < D_; k0 += 32) {
        #pragma unroll
        for (int i = 0; i < 2; ++i) {
            int slot = t + i * 256;
            int row = slot >> 2;
            int kc = (slot & 3) << 3;
            load16(A + (size_t)(m0 + row) * D_ + k0 + kc, lA + slot * 8);
            load16(Bt + (size_t)(n0 + row) * D_ + k0 + kc, lB + slot * 8);
        }
        __syncthreads();
        bf16x8 af[4], bfr[4];
        #pragma unroll
        for (int mi = 0; mi < 4; ++mi)
            af[mi] = *(const bf16x8*)(lA + (wm + mi * 16 + col) * 32 + quad * 8);
        #pragma unroll
        for (int ni = 0; ni < 4; ++ni)
            bfr[ni] = *(const bf16x8*)(lB + (wn + ni * 16 + col) * 32 + quad * 8);
        #pragma unroll
        for (int mi = 0; mi < 4; ++mi)
            #pragma unroll
            for (int ni = 0; ni < 4; ++ni)
                acc[mi][ni] = __builtin_amdgcn_mfma_f32_16x16x32_bf16(
                    af[mi], bfr[ni], acc[mi][ni], 0, 0, 0);
        __syncthreads();
    }
}

// ---------------- QKV projection ----------------
// mode 0: Q scaled by (1/8)*log2(e) -> [b][h][s][hd]; mode 1: K; mode 2: V^T
__global__ __launch_bounds__(256) void gemm_qkv_k(
    const bf16* __restrict__ X, const bf16* __restrict__ WT,
    const bf16* __restrict__ BN,
    bf16* __restrict__ Qo, bf16* __restrict__ Ko, bf16* __restrict__ Vo)
{
    __shared__ __align__(16) bf16 lA[128 * 32];
    __shared__ __align__(16) bf16 lB[128 * 32];
    const int mode = blockIdx.z;
    const bf16* Wsel = WT + ((size_t)mode << 20);
    const bf16* bias = BN + mode * 1024;
    f32x4 acc[4][4];
    const f32x4 z = {0.f, 0.f, 0.f, 0.f};
    #pragma unroll
    for (int i = 0; i < 4; ++i)
        #pragma unroll
        for (int j = 0; j < 4; ++j) acc[i][j] = z;
    const int m0 = blockIdx.x * 128, n0 = blockIdx.y * 128;
    gemm_core(X, Wsel, lA, lB, acc, m0, n0);
    const int t = threadIdx.x, lane = t & 63, wave = t >> 6;
    const int wm = (wave >> 1) << 6, wn = (wave & 1) << 6;
    const int quad = lane >> 4, col = lane & 15;
    // 0.125 * log2(e): softmax later uses raw exp2
    const float scale = (mode == 0) ? 0.18033688011112042f : 1.0f;
    #pragma unroll
    for (int mi = 0; mi < 4; ++mi) {
        int gm = m0 + wm + mi * 16 + quad * 4;
        int b = gm >> 11, srow = gm & 2047;
        #pragma unroll
        for (int ni = 0; ni < 4; ++ni) {
            int gn = n0 + wn + ni * 16 + col;
            float bb = (float)bias[gn];
            int h = gn >> 6, hd = gn & 63;
            if (mode == 2) {
                // V^T: 4 r-values are contiguous in s -> one 8B store
                Pack4 pk;
                #pragma unroll
                for (int r = 0; r < 4; ++r)
                    pk.b[r] = (bf16)(acc[mi][ni][r] + bb);
                *(uint2*)(Vo + (((size_t)b * H_ + h) * HD_ + hd) * S_ + srow)
                    = pk.q;
            } else {
                #pragma unroll
                for (int r = 0; r < 4; ++r) {
                    float v = (acc[mi][ni][r] + bb) * scale;
                    if (mode == 1)
                        Ko[(((size_t)b * H_ + h) * S_ + srow + r) * HD_ + hd] = (bf16)v;
                    else
                        Qo[(((size_t)b * H_ + h) * S_ + srow + r) * HD_ + hd] = (bf16)v;
                }
            }
        }
    }
}

// ---------------- flash attention (causal), S^T/O^T form, dbuf staging -------
// grid: (S/64, B*H). block: 256 = 4 waves; wave w owns 16 q rows. K-tile = 64.
// S^T = K·Q^T; O^T = V^T·P^T. XOR-swizzled LDS. Double-buffered K/V staging:
// prefetch tile i+1, s_waitcnt vmcnt(4) (only tile i drained), raw s_barrier
// (avoids __syncthreads' forced vmcnt(0)), compute, barrier, flip.
__global__ __launch_bounds__(256) void attn_k(
    const bf16* __restrict__ Q, const bf16* __restrict__ K,
    const bf16* __restrict__ VT, bf16* __restrict__ Aout)
{
    __shared__ __align__(16) bf16 lK[2][64 * 64];   // [k][d], chunk^=(k&7)
    __shared__ __align__(16) bf16 lV[2][64 * 64];   // [d][k], chunk^=(d&7)
    __shared__ __align__(16) bf16 lPT[4][16 * 64];  // per-wave [q][k], ^=(q&7)
    const int bh = blockIdx.y;
    const int qc = (int)gridDim.x - 1 - (int)blockIdx.x; // big blocks first
    const int q0 = qc * 64;
    const bf16* Qp = Q + (size_t)bh * S_ * HD_;
    const bf16* Kp = K + (size_t)bh * S_ * HD_;
    const bf16* Vp = VT + (size_t)bh * HD_ * S_;
    const int t = threadIdx.x, lane = t & 63, w = t >> 6;
    const int quad = lane >> 4, col = lane & 15;
    const int wq0 = q0 + w * 16;

    // Q fragments (B-operand): B[n=q][k=d], n=col, k=quad*8+j
    bf16x8 qf[2];
    #pragma unroll
    for (int cc = 0; cc < 2; ++cc)
        qf[cc] = *(const bf16x8*)(Qp + (size_t)(wq0 + col) * HD_
                                  + cc * 32 + quad * 8);
    f32x4 o[4];               // O^T acc per d-tile; q = col
    float mst = NEG_SENT, lst = 0.f;
    const f32x4 z = {0.f, 0.f, 0.f, 0.f};
    #pragma unroll
    for (int dt = 0; dt < 4; ++dt) o[dt] = z;

    // stage tile 0 into buffer 0
    #pragma unroll
    for (int i = 0; i < 2; ++i) {
        int slot = t + i * 256;
        int rr = slot >> 3, ch = slot & 7;
        int sw = (ch ^ (rr & 7)) << 3;
        load16(Kp + (size_t)rr * HD_ + sw, lK[0] + slot * 8);
        load16(Vp + (size_t)rr * S_ + sw, lV[0] + slot * 8);
    }

    int p = 0;
    for (int k0 = 0; k0 <= q0; k0 += 64) {
        // prefetch next tile (clamped in-bounds) into the other buffer
        const int nk = (k0 + 64 <= q0) ? (k0 + 64) : q0;
        #pragma unroll
        for (int i = 0; i < 2; ++i) {
            int slot = t + i * 256;
            int rr = slot >> 3, ch = slot & 7;
            int sw = (ch ^ (rr & 7)) << 3;
            load16(Kp + (size_t)(nk + rr) * HD_ + sw, lK[p ^ 1] + slot * 8);
            load16(Vp + (size_t)rr * S_ + nk + sw, lV[p ^ 1] + slot * 8);
        }
        // wait only for tile-i's 4 loads (the 4 prefetch loads stay in flight)
        asm volatile("s_waitcnt vmcnt(4)" ::: "memory");
        asm volatile("s_barrier" ::: "memory");
        const bf16* K_ = lK[p];
        const bf16* V_ = lV[p];

        bool inc[4];
        inc[0] = true;
        inc[1] = (k0 + 16 <= wq0 + 15);
        inc[2] = (k0 + 32 <= wq0 + 15);
        inc[3] = (k0 + 48 <= wq0 + 15);
        // S^T[mt=k] = K·Q^T
        f32x4 st[4];
        #pragma unroll
        for (int mt = 0; mt < 4; ++mt) st[mt] = z;
        #pragma unroll
        for (int cc = 0; cc < 2; ++cc) {
            #pragma unroll
            for (int mt = 0; mt < 4; ++mt)
                if (inc[mt]) {
                    bf16x8 af = *(const bf16x8*)(K_ + (mt * 16 + col) * 64
                                + (((cc * 4 + quad) ^ (col & 7)) << 3));
                    st[mt] = __builtin_amdgcn_mfma_f32_16x16x32_bf16(
                        af, qf[cc], st[mt], 0, 0, 0);
                }
        }
        if (k0 + 64 > wq0) { // diagonal region: mask k > q
            #pragma unroll
            for (int mt = 0; mt < 4; ++mt)
                if (inc[mt]) {
                    #pragma unroll
                    for (int r = 0; r < 4; ++r)
                        if (k0 + mt * 16 + quad * 4 + r > wq0 + col)
                            st[mt][r] = NEG_SENT;
                }
        }
        // online softmax per q (= col): reg reduce + 2 shuffles
        float tm = fmaxf(fmaxf(st[0][0], st[0][1]),
                         fmaxf(st[0][2], st[0][3]));
        #pragma unroll
        for (int mt = 1; mt < 4; ++mt)
            if (inc[mt]) {
                #pragma unroll
                for (int r = 0; r < 4; ++r) tm = fmaxf(tm, st[mt][r]);
            }
        tm = fmaxf(tm, __shfl_xor(tm, 16));
        tm = fmaxf(tm, __shfl_xor(tm, 32));
        float mn = fmaxf(mst, tm);
        float al = exp2f(mst - mn);
        mst = mn;
        float ssum = 0.f;
        #pragma unroll
        for (int mt = 0; mt < 4; ++mt)
            if (inc[mt]) {
                #pragma unroll
                for (int r = 0; r < 4; ++r) {
                    float pv = exp2f(st[mt][r] - mn);
                    st[mt][r] = pv;
                    ssum += pv;
                }
            }
        ssum += __shfl_xor(ssum, 16);
        ssum += __shfl_xor(ssum, 32);
        lst = lst * al + ssum;
        #pragma unroll
        for (int dt = 0; dt < 4; ++dt) o[dt] *= al;
        // P^T -> lPT[w] as [q][k]; zero-fill excluded tile a live PV read uses
        #pragma unroll
        for (int mt = 0; mt < 4; ++mt) {
            int kch = mt * 2 + (quad >> 1);
            uint2* dst = (uint2*)(&lPT[w][col * 64 + ((kch ^ (col & 7)) << 3)
                                         + ((quad & 1) << 2)]);
            if (inc[mt]) {
                Pack4 pk;
                #pragma unroll
                for (int r = 0; r < 4; ++r) pk.b[r] = (bf16)st[mt][r];
                *dst = pk.q;
            } else if (mt == 1 || (mt == 3 && inc[2])) {
                uint2 zz; zz.x = 0u; zz.y = 0u;
                *dst = zz;
            }
        }
        // drain P writes before same-wave cross-lane reads
        asm volatile("s_waitcnt lgkmcnt(0)" ::: "memory");
        // O^T += V^T · P^T
        #pragma unroll
        for (int kk = 0; kk < 2; ++kk) {
            if (kk == 1 && !inc[2]) continue;
            bf16x8 pf = *(const bf16x8*)(&lPT[w][col * 64
                        + (((kk * 4 + quad) ^ (col & 7)) << 3)]);
            #pragma unroll
            for (int dt = 0; dt < 4; ++dt) {
                bf16x8 vf = *(const bf16x8*)(V_ + (dt * 16 + col) * 64
                            + (((kk * 4 + quad) ^ (col & 7)) << 3));
                o[dt] = __builtin_amdgcn_mfma_f32_16x16x32_bf16(
                    vf, pf, o[dt], 0, 0, 0);
            }
        }
        // all waves done reading buf p before next prefetch overwrites it
        asm volatile("s_barrier" ::: "memory");
        p ^= 1;
    }
    const int b = bh >> 4, h = bh & 15;
    const float inv = 1.f / fmaxf(lst, 1e-30f);
    const int qg = wq0 + col;
    #pragma unroll
    for (int dt = 0; dt < 4; ++dt) {
        Pack4 pk;
        #pragma unroll
        for (int r = 0; r < 4; ++r) pk.b[r] = (bf16)(o[dt][r] * inv);
        *(uint2*)(Aout + ((size_t)b * S_ + qg) * D_ + h * HD_
                  + dt * 16 + quad * 4) = pk.q;
    }
}

// ---------------- output projection (dtype-aware store) ----------------
__global__ __launch_bounds__(256) void gemm_out_k(
    const bf16* __restrict__ A, const bf16* __restrict__ WoT,
    const bf16* __restrict__ Bo, void* __restrict__ Out,
    const int* __restrict__ flag)
{
    __shared__ __align__(16) bf16 lA[128 * 32];
    __shared__ __align__(16) bf16 lB[128 * 32];
    f32x4 acc[4][4];
    const f32x4 z = {0.f, 0.f, 0.f, 0.f};
    #pragma unroll
    for (int i = 0; i < 4; ++i)
        #pragma unroll
        for (int j = 0; j < 4; ++j) acc[i][j] = z;
    const int m0 = blockIdx.x * 128, n0 = blockIdx.y * 128;
    gemm_core(A, WoT, lA, lB, acc, m0, n0);
    const int t = threadIdx.x, lane = t & 63, wave = t >> 6;
    const int wm = (wave >> 1) << 6, wn = (wave & 1) << 6;
    const int quad = lane >> 4, col = lane & 15;
    const int isb = *flag;
    #pragma unroll
    for (int mi = 0; mi < 4; ++mi) {
        int gm = m0 + wm + mi * 16 + quad * 4;
        #pragma unroll
        for (int ni = 0; ni < 4; ++ni) {
            int gn = n0 + wn + ni * 16 + col;
            float bb = (float)Bo[gn];
            #pragma unroll
            for (int r = 0; r < 4; ++r) {
                float v = acc[mi][ni][r] + bb;
                size_t off = (size_t)(gm + r) * D_ + gn;
                if (isb) ((bf16*)Out)[off] = (bf16)v;
                else     ((float*)Out)[off] = v;
            }
        }
    }
}

extern "C" void kernel_launch(void* const* d_in, const int* in_sizes, int n_in,
                              void* d_out, int out_size, void* d_ws, size_t ws_size,
                              hipStream_t stream)
{
    const void* x  = d_in[0];
    const void* wq = d_in[1];
    const void* bq = d_in[2];
    const void* wk = d_in[3];
    const void* bk = d_in[4];
    const void* wv = d_in[5];
    const void* bv = d_in[6];
    const void* wo = d_in[7];
    const void* bo = d_in[8];

    bf16* ws  = (bf16*)d_ws;
    bf16* XN  = ws + XN_OFF;                 // also reused as Ab
    bf16* WT  = ws + WT_OFF;
    bf16* BN  = ws + BN_OFF;
    int*  flag = (int*)((char*)d_ws + FLAG_BYTE);
    bf16* Qb  = ws + Q_OFF;
    bf16* Kb  = ws + K_OFF;
    bf16* VTb = ws + VT_OFF;
    bf16* Ab  = XN;

    hipLaunchKernelGGL(detect_k, dim3(1), dim3(256), 0, stream,
                       (const u16*)x, flag);
    hipLaunchKernelGGL(norm_x_k, dim3(8192), dim3(256), 0, stream,
                       x, XN, flag);
    hipLaunchKernelGGL(transpose_w, dim3(16, 16, 4), dim3(256), 0, stream,
                       wq, wk, wv, wo, WT, flag);
    hipLaunchKernelGGL(norm_b_k, dim3(4), dim3(256), 0, stream,
                       bq, bk, bv, bo, BN, flag);
    hipLaunchKernelGGL(gemm_qkv_k, dim3(64, 8, 3), dim3(256), 0, stream,
                       XN, WT, BN, Qb, Kb, VTb);
    hipLaunchKernelGGL(attn_k, dim3(32, 64), dim3(256), 0, stream,
                       Qb, Kb, VTb, Ab);
    hipLaunchKernelGGL(gemm_out_k, dim3(64, 8), dim3(256), 0, stream,
                       Ab, WT + ((size_t)3u << 20), BN + 3072, d_out, flag);
}

// Round 9
// 304.021 us; speedup vs baseline: 2.3901x; 1.2565x over previous
//
#include <hip/hip_runtime.h>
#include <hip/hip_bf16.h>

typedef __bf16 bf16;
typedef bf16 bf16x8 __attribute__((ext_vector_type(8)));
typedef float f32x4 __attribute__((ext_vector_type(4)));
typedef unsigned short u16;

#define B_ 4
#define S_ 2048
#define D_ 1024
#define H_ 16
#define HD_ 64

#define NEG_SENT -30000.0f

// workspace layout (bf16 element offsets)
#define XN_OFF   ((size_t)0)          // 8388608 elems; reused as Ab after QKV
#define WT_OFF   ((size_t)8388608)    // 4 x 1048576
#define BN_OFF   ((size_t)12582912)   // 4 x 1024
#define FLAG_BYTE ((size_t)25174016)  // int flag
#define Q_OFF    ((size_t)12587520)
#define K_OFF    ((size_t)20976128)
#define VT_OFF   ((size_t)29364736)

union Pack4 { bf16 b[4]; uint2 q; };

__device__ __forceinline__ void load16(const bf16* g, bf16* l) {
    __builtin_amdgcn_global_load_lds(
        (const __attribute__((address_space(1))) void*)g,
        (__attribute__((address_space(3))) void*)l, 16, 0, 0);
}

// ---------------- dtype detection ----------------
__global__ __launch_bounds__(256) void detect_k(const u16* __restrict__ x,
                                                int* __restrict__ flag)
{
    __shared__ int cnt;
    if (threadIdx.x == 0) cnt = 0;
    __syncthreads();
    int c = 0;
    for (int i = threadIdx.x; i < 4096; i += 256) {
        u16 w = x[i * 2];            // even-indexed words
        int e = (w >> 7) & 0xFF;
        if (e >= 100 && e <= 135) c++;
    }
    atomicAdd(&cnt, c);
    __syncthreads();
    if (threadIdx.x == 0) *flag = (cnt > 2048) ? 1 : 0;   // 1 = bf16
}

// ---------------- input normalization: x -> bf16 XN ----------------
__global__ __launch_bounds__(256) void norm_x_k(const void* __restrict__ src,
                                                bf16* __restrict__ dst,
                                                const int* __restrict__ flag)
{
    const int qi = blockIdx.x * 256 + threadIdx.x;   // quad index, 4 elems each
    if (*flag) {
        ((uint2*)dst)[qi] = ((const uint2*)src)[qi];
    } else {
        float4 v = ((const float4*)src)[qi];
        Pack4 p;
        p.b[0] = (bf16)v.x; p.b[1] = (bf16)v.y;
        p.b[2] = (bf16)v.z; p.b[3] = (bf16)v.w;
        ((uint2*)dst)[qi] = p.q;
    }
}

// ---------------- bias normalization ----------------
__global__ __launch_bounds__(256) void norm_b_k(
    const void* __restrict__ b0, const void* __restrict__ b1,
    const void* __restrict__ b2, const void* __restrict__ b3,
    bf16* __restrict__ BN, const int* __restrict__ flag)
{
    const int mat = blockIdx.x;
    const void* src = (mat == 0) ? b0 : (mat == 1) ? b1 : (mat == 2) ? b2 : b3;
    bf16* dst = BN + mat * 1024;
    const int i = threadIdx.x * 4;
    if (*flag) {
        ((uint2*)(dst + i))[0] = *(const uint2*)((const bf16*)src + i);
    } else {
        const float* s = (const float*)src;
        Pack4 p;
        p.b[0] = (bf16)s[i + 0]; p.b[1] = (bf16)s[i + 1];
        p.b[2] = (bf16)s[i + 2]; p.b[3] = (bf16)s[i + 3];
        ((uint2*)(dst + i))[0] = p.q;
    }
}

// ---------- weight normalize + transpose: W[K][N] -> WT[N][K] (bf16) ----------
__global__ __launch_bounds__(256) void transpose_w(
    const void* __restrict__ W0, const void* __restrict__ W1,
    const void* __restrict__ W2, const void* __restrict__ W3,
    bf16* __restrict__ WT, const int* __restrict__ flag)
{
    __shared__ __align__(16) bf16 tile[64][65];
    const int mat = blockIdx.z;
    const void* W = (mat == 0) ? W0 : (mat == 1) ? W1 : (mat == 2) ? W2 : W3;
    bf16* O = WT + ((size_t)mat << 20);
    const int r0 = blockIdx.y * 64, c0 = blockIdx.x * 64;
    const int t = threadIdx.x;
    const int isb = *flag;
    #pragma unroll
    for (int i = 0; i < 16; ++i) {
        int idx = t + i * 256;
        int r = idx >> 6, c = idx & 63;
        size_t off = (size_t)(r0 + r) * D_ + c0 + c;
        tile[r][c] = isb ? ((const bf16*)W)[off] : (bf16)((const float*)W)[off];
    }
    __syncthreads();
    #pragma unroll
    for (int i = 0; i < 16; ++i) {
        int idx = t + i * 256;
        int rr = idx & 63, cc = idx >> 6;
        O[(size_t)(c0 + cc) * D_ + r0 + rr] = tile[rr][cc];
    }
}

// ---------------- shared 128x128 GEMM mainloop (m97 structure) ----------------
__device__ __forceinline__ void gemm_core(const bf16* __restrict__ A,
                                          const bf16* __restrict__ Bt,
                                          bf16* lA, bf16* lB,
                                          f32x4 acc[4][4], int m0, int n0)
{
    const int t = threadIdx.x;
    const int lane = t & 63;
    const int wave = t >> 6;
    const int wm = (wave >> 1) << 6;
    const int wn = (wave & 1) << 6;
    const int quad = lane >> 4;
    const int col = lane & 15;
    for (int k0 = 0; k0 < D_; k0 += 32) {
        #pragma unroll
        for (int i = 0; i < 2; ++i) {
            int slot = t + i * 256;
            int row = slot >> 2;
            int kc = (slot & 3) << 3;
            load16(A + (size_t)(m0 + row) * D_ + k0 + kc, lA + slot * 8);
            load16(Bt + (size_t)(n0 + row) * D_ + k0 + kc, lB + slot * 8);
        }
        __syncthreads();
        bf16x8 af[4], bfr[4];
        #pragma unroll
        for (int mi = 0; mi < 4; ++mi)
            af[mi] = *(const bf16x8*)(lA + (wm + mi * 16 + col) * 32 + quad * 8);
        #pragma unroll
        for (int ni = 0; ni < 4; ++ni)
            bfr[ni] = *(const bf16x8*)(lB + (wn + ni * 16 + col) * 32 + quad * 8);
        #pragma unroll
        for (int mi = 0; mi < 4; ++mi)
            #pragma unroll
            for (int ni = 0; ni < 4; ++ni)
                acc[mi][ni] = __builtin_amdgcn_mfma_f32_16x16x32_bf16(
                    af[mi], bfr[ni], acc[mi][ni], 0, 0, 0);
        __syncthreads();
    }
}

// ---------------- QKV projection ----------------
// mode 0: Q scaled by (1/8)*log2(e) -> [b][h][s][hd]; mode 1: K; mode 2: V^T
__global__ __launch_bounds__(256) void gemm_qkv_k(
    const bf16* __restrict__ X, const bf16* __restrict__ WT,
    const bf16* __restrict__ BN,
    bf16* __restrict__ Qo, bf16* __restrict__ Ko, bf16* __restrict__ Vo)
{
    __shared__ __align__(16) bf16 lA[128 * 32];
    __shared__ __align__(16) bf16 lB[128 * 32];
    const int mode = blockIdx.z;
    const bf16* Wsel = WT + ((size_t)mode << 20);
    const bf16* bias = BN + mode * 1024;
    f32x4 acc[4][4];
    const f32x4 z = {0.f, 0.f, 0.f, 0.f};
    #pragma unroll
    for (int i = 0; i < 4; ++i)
        #pragma unroll
        for (int j = 0; j < 4; ++j) acc[i][j] = z;
    const int m0 = blockIdx.x * 128, n0 = blockIdx.y * 128;
    gemm_core(X, Wsel, lA, lB, acc, m0, n0);
    const int t = threadIdx.x, lane = t & 63, wave = t >> 6;
    const int wm = (wave >> 1) << 6, wn = (wave & 1) << 6;
    const int quad = lane >> 4, col = lane & 15;
    // 0.125 * log2(e): softmax later uses raw exp2
    const float scale = (mode == 0) ? 0.18033688011112042f : 1.0f;
    #pragma unroll
    for (int mi = 0; mi < 4; ++mi) {
        int gm = m0 + wm + mi * 16 + quad * 4;
        int b = gm >> 11, srow = gm & 2047;
        #pragma unroll
        for (int ni = 0; ni < 4; ++ni) {
            int gn = n0 + wn + ni * 16 + col;
            float bb = (float)bias[gn];
            int h = gn >> 6, hd = gn & 63;
            if (mode == 2) {
                // V^T: 4 r-values are contiguous in s -> one 8B store
                Pack4 pk;
                #pragma unroll
                for (int r = 0; r < 4; ++r)
                    pk.b[r] = (bf16)(acc[mi][ni][r] + bb);
                *(uint2*)(Vo + (((size_t)b * H_ + h) * HD_ + hd) * S_ + srow)
                    = pk.q;
            } else {
                #pragma unroll
                for (int r = 0; r < 4; ++r) {
                    float v = (acc[mi][ni][r] + bb) * scale;
                    if (mode == 1)
                        Ko[(((size_t)b * H_ + h) * S_ + srow + r) * HD_ + hd] = (bf16)v;
                    else
                        Qo[(((size_t)b * H_ + h) * S_ + srow + r) * HD_ + hd] = (bf16)v;
                }
            }
        }
    }
}

// ---- one 64-row q-tile, verbatim R5 body (proven absmax 0.0078) ------------
__device__ __forceinline__ void attn_tile(
    const bf16* __restrict__ Qp, const bf16* __restrict__ Kp,
    const bf16* __restrict__ Vp, bf16* __restrict__ Aout,
    int b, int h, int q0,
    bf16* lK, bf16* lV, bf16* lPTw)
{
    const int t = threadIdx.x, lane = t & 63, w = t >> 6;
    const int quad = lane >> 4, col = lane & 15;
    const int wq0 = q0 + w * 16;

    // Q fragments (B-operand): B[n=q][k=d], n=col, k=quad*8+j
    bf16x8 qf[2];
    #pragma unroll
    for (int cc = 0; cc < 2; ++cc)
        qf[cc] = *(const bf16x8*)(Qp + (size_t)(wq0 + col) * HD_
                                  + cc * 32 + quad * 8);
    f32x4 o[4];               // O^T acc per d-tile; q = col
    float mst = NEG_SENT, lst = 0.f;
    const f32x4 z = {0.f, 0.f, 0.f, 0.f};
    #pragma unroll
    for (int dt = 0; dt < 4; ++dt) o[dt] = z;

    const int kend = q0 + 64;
    for (int k0 = 0; k0 < kend; k0 += 64) {
        // stage K[k0:+64][0:64] and V^T[0:64][k0:+64], xor-swizzled 8-chunks
        #pragma unroll
        for (int i = 0; i < 2; ++i) {
            int slot = t + i * 256;          // 0..511
            int rr = slot >> 3, ch = slot & 7;
            int sw = (ch ^ (rr & 7)) << 3;
            load16(Kp + (size_t)(k0 + rr) * HD_ + sw, lK + slot * 8);
            load16(Vp + (size_t)rr * S_ + k0 + sw, lV + slot * 8);
        }
        __syncthreads();
        if (k0 < wq0 + 16) {
            bool inc[4];
            inc[0] = true;
            inc[1] = (k0 + 16 <= wq0 + 15);
            inc[2] = (k0 + 32 <= wq0 + 15);
            inc[3] = (k0 + 48 <= wq0 + 15);
            // S^T[mt=k] = K·Q^T
            f32x4 st[4];
            #pragma unroll
            for (int mt = 0; mt < 4; ++mt) st[mt] = z;
            #pragma unroll
            for (int cc = 0; cc < 2; ++cc) {
                #pragma unroll
                for (int mt = 0; mt < 4; ++mt)
                    if (inc[mt]) {
                        bf16x8 af = *(const bf16x8*)(lK + (mt * 16 + col) * 64
                                    + (((cc * 4 + quad) ^ (col & 7)) << 3));
                        st[mt] = __builtin_amdgcn_mfma_f32_16x16x32_bf16(
                            af, qf[cc], st[mt], 0, 0, 0);
                    }
            }
            if (k0 + 64 > wq0) { // diagonal region: mask k > q
                #pragma unroll
                for (int mt = 0; mt < 4; ++mt)
                    if (inc[mt]) {
                        #pragma unroll
                        for (int r = 0; r < 4; ++r)
                            if (k0 + mt * 16 + quad * 4 + r > wq0 + col)
                                st[mt][r] = NEG_SENT;
                    }
            }
            // online softmax per q (= col): reg reduce + 2 shuffles
            float tm = fmaxf(fmaxf(st[0][0], st[0][1]),
                             fmaxf(st[0][2], st[0][3]));
            #pragma unroll
            for (int mt = 1; mt < 4; ++mt)
                if (inc[mt]) {
                    #pragma unroll
                    for (int r = 0; r < 4; ++r) tm = fmaxf(tm, st[mt][r]);
                }
            tm = fmaxf(tm, __shfl_xor(tm, 16));
            tm = fmaxf(tm, __shfl_xor(tm, 32));
            float mn = fmaxf(mst, tm);
            float al = exp2f(mst - mn);
            mst = mn;
            float ssum = 0.f;
            #pragma unroll
            for (int mt = 0; mt < 4; ++mt)
                if (inc[mt]) {
                    #pragma unroll
                    for (int r = 0; r < 4; ++r) {
                        float pv = exp2f(st[mt][r] - mn);
                        st[mt][r] = pv;
                        ssum += pv;
                    }
                }
            ssum += __shfl_xor(ssum, 16);
            ssum += __shfl_xor(ssum, 32);
            lst = lst * al + ssum;
            #pragma unroll
            for (int dt = 0; dt < 4; ++dt) o[dt] *= al;
            // P^T -> lPTw as [q][k]; zero-fill excluded tile a live PV read uses
            #pragma unroll
            for (int mt = 0; mt < 4; ++mt) {
                int kch = mt * 2 + (quad >> 1);
                uint2* dst = (uint2*)(&lPTw[col * 64 + ((kch ^ (col & 7)) << 3)
                                            + ((quad & 1) << 2)]);
                if (inc[mt]) {
                    Pack4 pk;
                    #pragma unroll
                    for (int r = 0; r < 4; ++r) pk.b[r] = (bf16)st[mt][r];
                    *dst = pk.q;
                } else if (mt == 1 || (mt == 3 && inc[2])) {
                    uint2 zz; zz.x = 0u; zz.y = 0u;
                    *dst = zz;
                }
            }
            // drain P writes before same-wave cross-lane reads
            asm volatile("s_waitcnt lgkmcnt(0)" ::: "memory");
            // O^T += V^T · P^T
            #pragma unroll
            for (int kk = 0; kk < 2; ++kk) {
                if (kk == 1 && !inc[2]) continue;
                bf16x8 pf = *(const bf16x8*)(&lPTw[col * 64
                            + (((kk * 4 + quad) ^ (col & 7)) << 3)]);
                #pragma unroll
                for (int dt = 0; dt < 4; ++dt) {
                    bf16x8 vf = *(const bf16x8*)(lV + (dt * 16 + col) * 64
                                + (((kk * 4 + quad) ^ (col & 7)) << 3));
                    o[dt] = __builtin_amdgcn_mfma_f32_16x16x32_bf16(
                        vf, pf, o[dt], 0, 0, 0);
                }
            }
        }
        __syncthreads();
    }
    const float inv = 1.f / fmaxf(lst, 1e-30f);
    const int qg = wq0 + col;
    #pragma unroll
    for (int dt = 0; dt < 4; ++dt) {
        Pack4 pk;
        #pragma unroll
        for (int r = 0; r < 4; ++r) pk.b[r] = (bf16)(o[dt][r] * inv);
        *(uint2*)(Aout + ((size_t)b * S_ + qg) * D_ + h * HD_
                  + dt * 16 + quad * 4) = pk.q;
    }
}

// ---------------- flash attention (causal), paired q-tiles, sequential ------
// grid: (16, B*H). Block i runs q-tile 31-i (long) then q-tile i (short):
// (32-i) + (i+1) = 33 k-iterations per block -> perfectly uniform work,
// 1024 blocks = 4/CU all co-resident, zero tail. Bodies verbatim R5.
__global__ __launch_bounds__(256) void attn_k(
    const bf16* __restrict__ Q, const bf16* __restrict__ K,
    const bf16* __restrict__ VT, bf16* __restrict__ Aout)
{
    __shared__ __align__(16) bf16 lK[64 * 64];      // [k][d], chunk^=(k&7)
    __shared__ __align__(16) bf16 lV[64 * 64];      // [d][k], chunk^=(d&7)
    __shared__ __align__(16) bf16 lPT[4][16 * 64];  // per-wave [q][k], ^=(q&7)
    const int bh = blockIdx.y;
    const bf16* Qp = Q + (size_t)bh * S_ * HD_;
    const bf16* Kp = K + (size_t)bh * S_ * HD_;
    const bf16* Vp = VT + (size_t)bh * HD_ * S_;
    const int b = bh >> 4, h = bh & 15;
    const int w = threadIdx.x >> 6;
    bf16* lPTw = &lPT[w][0];

    attn_tile(Qp, Kp, Vp, Aout, b, h, (31 - (int)blockIdx.x) * 64,
              lK, lV, lPTw);
    // trailing __syncthreads of the loop above orders LDS reuse; epilogue
    // global stores don't touch LDS.
    attn_tile(Qp, Kp, Vp, Aout, b, h, (int)blockIdx.x * 64,
              lK, lV, lPTw);
}

// ---------------- output projection (dtype-aware store) ----------------
__global__ __launch_bounds__(256) void gemm_out_k(
    const bf16* __restrict__ A, const bf16* __restrict__ WoT,
    const bf16* __restrict__ Bo, void* __restrict__ Out,
    const int* __restrict__ flag)
{
    __shared__ __align__(16) bf16 lA[128 * 32];
    __shared__ __align__(16) bf16 lB[128 * 32];
    f32x4 acc[4][4];
    const f32x4 z = {0.f, 0.f, 0.f, 0.f};
    #pragma unroll
    for (int i = 0; i < 4; ++i)
        #pragma unroll
        for (int j = 0; j < 4; ++j) acc[i][j] = z;
    const int m0 = blockIdx.x * 128, n0 = blockIdx.y * 128;
    gemm_core(A, WoT, lA, lB, acc, m0, n0);
    const int t = threadIdx.x, lane = t & 63, wave = t >> 6;
    const int wm = (wave >> 1) << 6, wn = (wave & 1) << 6;
    const int quad = lane >> 4, col = lane & 15;
    const int isb = *flag;
    #pragma unroll
    for (int mi = 0; mi < 4; ++mi) {
        int gm = m0 + wm + mi * 16 + quad * 4;
        #pragma unroll
        for (int ni = 0; ni < 4; ++ni) {
            int gn = n0 + wn + ni * 16 + col;
            float bb = (float)Bo[gn];
            #pragma unroll
            for (int r = 0; r < 4; ++r) {
                float v = acc[mi][ni][r] + bb;
                size_t off = (size_t)(gm + r) * D_ + gn;
                if (isb) ((bf16*)Out)[off] = (bf16)v;
                else     ((float*)Out)[off] = v;
            }
        }
    }
}

extern "C" void kernel_launch(void* const* d_in, const int* in_sizes, int n_in,
                              void* d_out, int out_size, void* d_ws, size_t ws_size,
                              hipStream_t stream)
{
    const void* x  = d_in[0];
    const void* wq = d_in[1];
    const void* bq = d_in[2];
    const void* wk = d_in[3];
    const void* bk = d_in[4];
    const void* wv = d_in[5];
    const void* bv = d_in[6];
    const void* wo = d_in[7];
    const void* bo = d_in[8];

    bf16* ws  = (bf16*)d_ws;
    bf16* XN  = ws + XN_OFF;                 // also reused as Ab
    bf16* WT  = ws + WT_OFF;
    bf16* BN  = ws + BN_OFF;
    int*  flag = (int*)((char*)d_ws + FLAG_BYTE);
    bf16* Qb  = ws + Q_OFF;
    bf16* Kb  = ws + K_OFF;
    bf16* VTb = ws + VT_OFF;
    bf16* Ab  = XN;

    hipLaunchKernelGGL(detect_k, dim3(1), dim3(256), 0, stream,
                       (const u16*)x, flag);
    hipLaunchKernelGGL(norm_x_k, dim3(8192), dim3(256), 0, stream,
                       x, XN, flag);
    hipLaunchKernelGGL(transpose_w, dim3(16, 16, 4), dim3(256), 0, stream,
                       wq, wk, wv, wo, WT, flag);
    hipLaunchKernelGGL(norm_b_k, dim3(4), dim3(256), 0, stream,
                       bq, bk, bv, bo, BN, flag);
    hipLaunchKernelGGL(gemm_qkv_k, dim3(64, 8, 3), dim3(256), 0, stream,
                       XN, WT, BN, Qb, Kb, VTb);
    hipLaunchKernelGGL(attn_k, dim3(16, 64), dim3(256), 0, stream,
                       Qb, Kb, VTb, Ab);
    hipLaunchKernelGGL(gemm_out_k, dim3(64, 8), dim3(256), 0, stream,
                       Ab, WT + ((size_t)3u << 20), BN + 3072, d_out, flag);
}